// Round 1
// baseline (8561.779 us; speedup 1.0000x reference)
//
#include <hip/hip_runtime.h>
#include <stdint.h>

#define TT 512
#define BB 64
#define II 512
#define HH 1024
#define KT 1536   // concatenated K = I + H

typedef __attribute__((ext_vector_type(8))) _Float16 half8;
typedef __attribute__((ext_vector_type(4))) float f32x4;

__device__ __forceinline__ float fsig(float x)  { return 1.0f / (1.0f + __expf(-x)); }
__device__ __forceinline__ float ftanh(float x) { return 1.0f - 2.0f / (1.0f + __expf(2.0f * x)); }

// zero the 4*64 barrier flag words at the head of ws (ws is poisoned 0xAA each launch)
__global__ void lstm_init(uint32_t* ws) { ws[threadIdx.x] = 0u; }

// Persistent LSTM: 256 WGs = 4 batch-groups (16 batches) x 64 col-groups (16 h-cols x 4 gates).
// Weights live in VGPRs (fp16 MFMA B-frags). One flag-barrier per timestep per batch-group.
__global__ __launch_bounds__(256, 1)
void lstm_persist(const float* __restrict__ x,
                  const float* __restrict__ wii, const float* __restrict__ bii,
                  const float* __restrict__ wif_, const float* __restrict__ bif_,
                  const float* __restrict__ wig, const float* __restrict__ big_,
                  const float* __restrict__ wio, const float* __restrict__ bio,
                  const float* __restrict__ whi, const float* __restrict__ bhi,
                  const float* __restrict__ whf, const float* __restrict__ bhf,
                  const float* __restrict__ whg, const float* __restrict__ bhg,
                  const float* __restrict__ who, const float* __restrict__ bho,
                  float* __restrict__ out, uint8_t* __restrict__ ws)
{
  const int tid  = threadIdx.x;
  const int wid  = tid >> 6;      // wave 0..3 : K-split
  const int lane = tid & 63;
  const int quad = lane >> 4;
  const int lrow = lane & 15;

  const int wg   = blockIdx.x;
  const int gb   = wg >> 6;       // batch group 0..3
  const int gc   = wg & 63;       // col group 0..63
  const int b0   = gb << 4;
  const int col0 = gc << 4;

  const float* wi[4] = {wii, wif_, wig, wio};
  const float* wh[4] = {whi, whf, whg, who};
  const float* bi[4] = {bii, bif_, big_, bio};
  const float* bh[4] = {bhi, bhf, bhg, bho};

  uint32_t* flags = (uint32_t*)ws + (gb << 6);                 // 64 flags per group
  _Float16* zg    = (_Float16*)(ws + 4096) + gb * (2 * 16 * KT); // double-buffered [16][1536] fp16

  // ---- persistent weight fragments (B operand: B[k][n], n=lane&15, k=quad*8+j) ----
  const int kb = wid * 384;       // this wave's K-range
  half8 wfrag[12][4];
#pragma unroll
  for (int kk = 0; kk < 12; ++kk) {
    const int k = kb + kk * 32 + quad * 8;
#pragma unroll
    for (int g = 0; g < 4; ++g) {
      const float* wp = (k < II) ? (wi[g] + (size_t)(col0 + lrow) * II + k)
                                 : (wh[g] + (size_t)(col0 + lrow) * HH + (k - II));
      half8 v;
#pragma unroll
      for (int j = 0; j < 8; ++j) v[j] = (_Float16)wp[j];
      wfrag[kk][g] = v;
    }
  }

  // per-thread elementwise ownership: (tb, thc) = one (batch, h-col) cell
  const int tb   = tid >> 4;
  const int thc  = tid & 15;
  const int gcol = col0 + thc;
  float bias[4];
#pragma unroll
  for (int g = 0; g < 4; ++g) bias[g] = bi[g][gcol] + bh[g][gcol];

  float c = 0.0f, h = 0.0f;

  // ---- prologue: fill z buffer 0 = [x[0] ; h0=0] ----
  zg[tb * KT + II + gcol] = (_Float16)0.0f;
  if (tid < 128) {
    const int row = tid >> 3;
    const int kx  = (tid & 7) + (gc << 3);
    zg[row * KT + kx] = (_Float16)x[(size_t)(b0 + row) * II + kx];
  }

  auto barrier = [&](uint32_t target) {
    __syncthreads();   // compiler drains vmcnt before s_barrier -> our stores are in L2
    if (tid == 0)
      __hip_atomic_store(&flags[gc], target, __ATOMIC_RELEASE, __HIP_MEMORY_SCOPE_AGENT);
    if (tid < 64) {
      int guard = 0;
      for (;;) {
        uint32_t v = __hip_atomic_load(&flags[tid], __ATOMIC_RELAXED, __HIP_MEMORY_SCOPE_AGENT);
        if (__ballot((int)(v >= target)) == ~0ull) break;
        __builtin_amdgcn_s_sleep(1);
        if (++guard > (1 << 24)) break;   // safety valve: fail loud, not hang
      }
    }
    __syncthreads();
    __builtin_amdgcn_fence(__ATOMIC_ACQUIRE, "agent");  // invalidate so z reads see remote XCD writes
  };

  barrier(1u);

  __shared__ float red[16 * 288];  // [wave*4+gate] stride 288, quad stride 72 -> 2-way max (free)

#pragma unroll 1
  for (int t = 0; t < TT; ++t) {
    const int p = t & 1;
    const _Float16* zp = zg + p * (16 * KT);
    _Float16*       zn = zg + (1 - p) * (16 * KT);

    // A frags: A[m=lane&15][k=quad*8+j] from z[b][k]
    half8 af[12];
#pragma unroll
    for (int kk = 0; kk < 12; ++kk)
      af[kk] = *(const half8*)(zp + lrow * KT + kb + kk * 32 + quad * 8);

    f32x4 acc[4];
#pragma unroll
    for (int g = 0; g < 4; ++g) acc[g] = (f32x4){0.f, 0.f, 0.f, 0.f};
#pragma unroll
    for (int kk = 0; kk < 12; ++kk)
#pragma unroll
      for (int g = 0; g < 4; ++g)
        acc[g] = __builtin_amdgcn_mfma_f32_16x16x32_f16(af[kk], wfrag[kk][g], acc[g], 0, 0, 0);

    // cross-wave K reduction via LDS; D layout: row(m)=quad*4+r, col(n)=lane&15
#pragma unroll
    for (int g = 0; g < 4; ++g)
#pragma unroll
      for (int r = 0; r < 4; ++r)
        red[(wid * 4 + g) * 288 + quad * 72 + r * 16 + lrow] = acc[g][r];
    __syncthreads();

    float pre[4];
#pragma unroll
    for (int g = 0; g < 4; ++g) {
      float s = bias[g];
#pragma unroll
      for (int w = 0; w < 4; ++w)
        s += red[(w * 4 + g) * 288 + (tb >> 2) * 72 + (tb & 3) * 16 + thc];
      pre[g] = s;
    }

    const float it = fsig(pre[0]);
    const float ft = fsig(pre[1]);
    const float gt = ftanh(pre[2]);
    const float ot = fsig(pre[3]);
    c = ft * c + it * gt;
    h = ot * ftanh(c);

    out[((size_t)t * BB + b0 + tb) * HH + gcol] = h;

    if (t < TT - 1) {
      // publish h into next z buffer + copy next x slice (8 k's per col-group)
      zn[tb * KT + II + gcol] = (_Float16)h;
      if (tid < 128) {
        const int row = tid >> 3;
        const int kx  = (tid & 7) + (gc << 3);
        zn[row * KT + kx] = (_Float16)x[((size_t)(t + 1) * BB + b0 + row) * II + kx];
      }
      barrier((uint32_t)(t + 2));
    }
  }

  // tails: h_T then c_T, each [B][H]
  out[(size_t)TT * BB * HH + (size_t)(b0 + tb) * HH + gcol] = h;
  out[(size_t)TT * BB * HH + (size_t)BB * HH + (size_t)(b0 + tb) * HH + gcol] = c;
}

extern "C" void kernel_launch(void* const* d_in, const int* in_sizes, int n_in,
                              void* d_out, int out_size, void* d_ws, size_t ws_size,
                              hipStream_t stream) {
  const float* x    = (const float*)d_in[0];
  const float* wii  = (const float*)d_in[1];
  const float* bii  = (const float*)d_in[2];
  const float* wif_ = (const float*)d_in[3];
  const float* bif_ = (const float*)d_in[4];
  const float* wig  = (const float*)d_in[5];
  const float* big_ = (const float*)d_in[6];
  const float* wio  = (const float*)d_in[7];
  const float* bio  = (const float*)d_in[8];
  const float* whi  = (const float*)d_in[9];
  const float* bhi  = (const float*)d_in[10];
  const float* whf  = (const float*)d_in[11];
  const float* bhf  = (const float*)d_in[12];
  const float* whg  = (const float*)d_in[13];
  const float* bhg  = (const float*)d_in[14];
  const float* who  = (const float*)d_in[15];
  const float* bho  = (const float*)d_in[16];

  lstm_init<<<1, 256, 0, stream>>>((uint32_t*)d_ws);
  lstm_persist<<<256, 256, 0, stream>>>(x, wii, bii, wif_, bif_, wig, big_, wio, bio,
                                        whi, bhi, whf, bhf, whg, bhg, who, bho,
                                        (float*)d_out, (uint8_t*)d_ws);
}

// Round 2
// 5767.185 us; speedup vs baseline: 1.4846x; 1.4846x over previous
//
#include <hip/hip_runtime.h>
#include <stdint.h>

#define TT 512
#define BB 64
#define II 512
#define HH 1024

typedef __attribute__((ext_vector_type(8))) _Float16 half8;
typedef __attribute__((ext_vector_type(4))) float f32x4;

__device__ __forceinline__ float fsig(float x)  { return 1.0f / (1.0f + __expf(-x)); }
__device__ __forceinline__ float ftanh(float x) { return 1.0f - 2.0f / (1.0f + __expf(2.0f * x)); }

// zero the 4*64 barrier flag words at the head of ws (ws is poisoned 0xAA each launch)
__global__ void lstm_init(uint32_t* ws) { ws[threadIdx.x] = 0u; }

// Persistent LSTM: 256 WGs = 4 batch-groups (16 batches) x 64 col-groups (16 h-cols x 4 gates).
// Weights live in VGPRs as fp16 MFMA B-frags. Cross-WG h exchange goes through L3 via
// relaxed agent-scope atomics (sc0 sc1 bypass) -- NO fences, no wbl2/inv per step.
__global__ __launch_bounds__(256, 1)
void lstm_persist(const float* __restrict__ x,
                  const float* __restrict__ wii, const float* __restrict__ bii,
                  const float* __restrict__ wif_, const float* __restrict__ bif_,
                  const float* __restrict__ wig, const float* __restrict__ big_,
                  const float* __restrict__ wio, const float* __restrict__ bio,
                  const float* __restrict__ whi, const float* __restrict__ bhi,
                  const float* __restrict__ whf, const float* __restrict__ bhf,
                  const float* __restrict__ whg, const float* __restrict__ bhg,
                  const float* __restrict__ who, const float* __restrict__ bho,
                  float* __restrict__ out, uint8_t* __restrict__ ws)
{
  const int tid  = threadIdx.x;
  const int wid  = tid >> 6;      // wave 0..3 : K-split (K = 1536 = 512 x + 1024 h)
  const int lane = tid & 63;
  const int quad = lane >> 4;
  const int lrow = lane & 15;

  const int wg   = blockIdx.x;
  const int gb   = wg >> 6;       // batch group 0..3
  const int gc   = wg & 63;       // col group 0..63
  const int b0   = gb << 4;
  const int col0 = gc << 4;

  const float* wi[4] = {wii, wif_, wig, wio};
  const float* wh[4] = {whi, whf, whg, who};
  const float* bi[4] = {bii, bif_, big_, bio};
  const float* bh[4] = {bhi, bhf, bhg, bho};

  uint32_t* flags = (uint32_t*)ws + (gb << 6);                  // 64 flags per group
  _Float16* zg    = (_Float16*)(ws + 4096) + gb * (2 * 16 * HH); // double-buffered h: [16][1024] fp16

  // ---- persistent weight fragments (B operand: B[k][n], n=lane&15, k=quad*8+j) ----
  const int kb = wid * 384;       // this wave's K-range in concatenated K=[x(512); h(1024)]
  half8 wfrag[12][4];
#pragma unroll
  for (int kk = 0; kk < 12; ++kk) {
    const int k = kb + kk * 32 + quad * 8;
#pragma unroll
    for (int g = 0; g < 4; ++g) {
      const float* wp = (k < II) ? (wi[g] + (size_t)(col0 + lrow) * II + k)
                                 : (wh[g] + (size_t)(col0 + lrow) * HH + (k - II));
      half8 v;
#pragma unroll
      for (int j = 0; j < 8; ++j) v[j] = (_Float16)wp[j];
      wfrag[kk][g] = v;
    }
  }

  // per-thread elementwise ownership: (tb, thc) = one (batch, h-col) cell
  const int tb   = tid >> 4;
  const int thc  = tid & 15;
  const int gcol = col0 + thc;
  float bias[4];
#pragma unroll
  for (int g = 0; g < 4; ++g) bias[g] = bi[g][gcol] + bh[g][gcol];

  float c = 0.0f, h = 0.0f;

  __shared__ float red[16 * 288];  // quad stride 72 -> max 2-way bank alias (free)
  __shared__ __attribute__((aligned(16))) _Float16 hstage[256];

  auto poll = [&](uint32_t target) {
    int guard = 0;
    for (;;) {
      uint32_t v = __hip_atomic_load(&flags[lane], __ATOMIC_RELAXED, __HIP_MEMORY_SCOPE_AGENT);
      if (__ballot((int)(v >= target)) == ~0ull) break;
      __builtin_amdgcn_s_sleep(1);
      if (++guard > (1 << 22)) break;   // fail loud, not hang
    }
  };

  // ---- prologue: h0 = 0 -> zero z buffer 0 (each WG zeros 64 u64 of the 4096) ----
  if (wid == 0) {
    __hip_atomic_store((uint64_t*)zg + (gc * 64 + lane), (uint64_t)0,
                       __ATOMIC_RELAXED, __HIP_MEMORY_SCOPE_AGENT);
    asm volatile("s_waitcnt vmcnt(0)" ::: "memory");
    if (lane == 0)
      __hip_atomic_store(&flags[gc], 1u, __ATOMIC_RELAXED, __HIP_MEMORY_SCOPE_AGENT);
    poll(1u);
  }
  __syncthreads();

#pragma unroll 1
  for (int t = 0; t < TT; ++t) {
    const _Float16* zp = zg + (t & 1) * (16 * HH);
    _Float16*       zn = zg + ((t + 1) & 1) * (16 * HH);
    const float* xrow  = x + ((size_t)t * BB + b0 + lrow) * II;
    const _Float16* zrow = zp + lrow * HH;

    // A frags: A[m=lane&15][k=quad*8+j]; k<512 from x (cached fp32), else h via sc-atomic
    half8 af[12];
#pragma unroll
    for (int kk = 0; kk < 12; ++kk) {
      const int k = kb + kk * 32 + quad * 8;
      if (k < II) {
        f32x4 v0 = *(const f32x4*)(xrow + k);
        f32x4 v1 = *(const f32x4*)(xrow + k + 4);
        half8 v;
#pragma unroll
        for (int j = 0; j < 4; ++j) { v[j] = (_Float16)v0[j]; v[4 + j] = (_Float16)v1[j]; }
        af[kk] = v;
      } else {
        const uint64_t* p = (const uint64_t*)(zrow + (k - II));
        union { uint64_t u[2]; half8 v; } cv;
        cv.u[0] = __hip_atomic_load(p,     __ATOMIC_RELAXED, __HIP_MEMORY_SCOPE_AGENT);
        cv.u[1] = __hip_atomic_load(p + 1, __ATOMIC_RELAXED, __HIP_MEMORY_SCOPE_AGENT);
        af[kk] = cv.v;
      }
    }

    f32x4 acc[4];
#pragma unroll
    for (int g = 0; g < 4; ++g) acc[g] = (f32x4){0.f, 0.f, 0.f, 0.f};
#pragma unroll
    for (int kk = 0; kk < 12; ++kk)
#pragma unroll
      for (int g = 0; g < 4; ++g)
        acc[g] = __builtin_amdgcn_mfma_f32_16x16x32_f16(af[kk], wfrag[kk][g], acc[g], 0, 0, 0);

    // cross-wave K reduction via LDS; D layout: row(m)=quad*4+r, col(n)=lane&15
#pragma unroll
    for (int g = 0; g < 4; ++g)
#pragma unroll
      for (int r = 0; r < 4; ++r)
        red[(wid * 4 + g) * 288 + quad * 72 + r * 16 + lrow] = acc[g][r];
    __syncthreads();

    float pre[4];
#pragma unroll
    for (int g = 0; g < 4; ++g) {
      float s = bias[g];
#pragma unroll
      for (int w = 0; w < 4; ++w)
        s += red[(w * 4 + g) * 288 + (tb >> 2) * 72 + (tb & 3) * 16 + thc];
      pre[g] = s;
    }

    const float it = fsig(pre[0]);
    const float ft = fsig(pre[1]);
    const float gt = ftanh(pre[2]);
    const float ot = fsig(pre[3]);
    c = ft * c + it * gt;
    h = ot * ftanh(c);

    hstage[tb * 16 + thc] = (_Float16)h;          // LDS stage for coalesced publish
    out[((size_t)t * BB + b0 + tb) * HH + gcol] = h;

    if (t < TT - 1) {
      __syncthreads();   // hstage complete; all waves done reading zp
      if (wid == 0) {
        const int row = lane >> 2, c4 = (lane & 3) * 4;
        const uint64_t val = *(const uint64_t*)&hstage[row * 16 + c4];
        __hip_atomic_store((uint64_t*)(zn + row * HH + col0 + c4), val,
                           __ATOMIC_RELAXED, __HIP_MEMORY_SCOPE_AGENT);
        asm volatile("s_waitcnt vmcnt(0)" ::: "memory");   // z stores acked at L3
        if (lane == 0)
          __hip_atomic_store(&flags[gc], (uint32_t)(t + 2),
                             __ATOMIC_RELAXED, __HIP_MEMORY_SCOPE_AGENT);
        poll((uint32_t)(t + 2));
      }
      __syncthreads();
    }
  }

  // tails: h_T then c_T, each [B][H]
  out[(size_t)TT * BB * HH + (size_t)(b0 + tb) * HH + gcol] = h;
  out[(size_t)TT * BB * HH + (size_t)BB * HH + (size_t)(b0 + tb) * HH + gcol] = c;
}

extern "C" void kernel_launch(void* const* d_in, const int* in_sizes, int n_in,
                              void* d_out, int out_size, void* d_ws, size_t ws_size,
                              hipStream_t stream) {
  const float* x    = (const float*)d_in[0];
  const float* wii  = (const float*)d_in[1];
  const float* bii  = (const float*)d_in[2];
  const float* wif_ = (const float*)d_in[3];
  const float* bif_ = (const float*)d_in[4];
  const float* wig  = (const float*)d_in[5];
  const float* big_ = (const float*)d_in[6];
  const float* wio  = (const float*)d_in[7];
  const float* bio  = (const float*)d_in[8];
  const float* whi  = (const float*)d_in[9];
  const float* bhi  = (const float*)d_in[10];
  const float* whf  = (const float*)d_in[11];
  const float* bhf  = (const float*)d_in[12];
  const float* whg  = (const float*)d_in[13];
  const float* bhg  = (const float*)d_in[14];
  const float* who  = (const float*)d_in[15];
  const float* bho  = (const float*)d_in[16];

  lstm_init<<<1, 256, 0, stream>>>((uint32_t*)d_ws);
  lstm_persist<<<256, 256, 0, stream>>>(x, wii, bii, wif_, bif_, wig, big_, wio, bio,
                                        whi, bhi, whf, bhf, whg, bhg, who, bho,
                                        (float*)d_out, (uint8_t*)d_ws);
}